// Round 3
// baseline (1872.174 us; speedup 1.0000x reference)
//
#include <hip/hip_runtime.h>
#include <hip/hip_bf16.h>

// Problem constants: B=128, N=1024, E=16384, ENTITY=100000, EMB=100, HID=100

typedef unsigned int u32;
typedef float f2 __attribute__((ext_vector_type(2)));

__device__ __forceinline__ float bflo(u32 u) {
    union { u32 i; float f; } v; v.i = u << 16; return v.f;
}
__device__ __forceinline__ float bfhi(u32 u) {
    union { u32 i; float f; } v; v.i = u & 0xffff0000u; return v.f;
}
__device__ __forceinline__ u32 f2bf1(float f) {
    union { float f; u32 u; } v; v.f = f;
    return (v.u + 0x7fffu + ((v.u >> 16) & 1u)) >> 16;   // RNE
}
__device__ __forceinline__ u32 packbf(float a, float b) {
    return f2bf1(a) | (f2bf1(b) << 16);
}
__device__ __forceinline__ float sigm(float x) { return 1.f / (1.f + __expf(-x)); }
__device__ __forceinline__ float tanh_fast(float x) {
    float e = __expf(2.f * x);
    return 1.f - 2.f / (e + 1.f);
}

// ---------------------------------------------------------------------------
// Kernel 1: embedding gather + GCN matmul.  support[n][h] (bf16 packed u32)
// ---------------------------------------------------------------------------
__global__ __launch_bounds__(256, 2)
void gcn_kernel(const int* __restrict__ nb, const float* __restrict__ emb,
                const float* __restrict__ w, u32* __restrict__ support)
{
    __shared__ float wl[10000];
    for (int i = threadIdx.x; i < 10000; i += 256) wl[i] = w[i];
    __syncthreads();

    const int n = blockIdx.x * 256 + threadIdx.x;
    const long long row = nb[n];
    const float4* __restrict__ xr = (const float4*)(emb + row * 100);

    float acc[100];
#pragma unroll
    for (int h = 0; h < 100; ++h) acc[h] = 0.f;

    for (int kk = 0; kk < 25; ++kk) {
        const float4 xv = xr[kk];
        const float xs[4] = { xv.x, xv.y, xv.z, xv.w };
#pragma unroll
        for (int q = 0; q < 4; ++q) {
            const float* wrow = &wl[(kk * 4 + q) * 100];
            const float xq = xs[q];
#pragma unroll
            for (int h4 = 0; h4 < 25; ++h4) {
                const float4 w4 = *(const float4*)(wrow + h4 * 4);
                acc[h4*4+0] = fmaf(xq, w4.x, acc[h4*4+0]);
                acc[h4*4+1] = fmaf(xq, w4.y, acc[h4*4+1]);
                acc[h4*4+2] = fmaf(xq, w4.z, acc[h4*4+2]);
                acc[h4*4+3] = fmaf(xq, w4.w, acc[h4*4+3]);
            }
        }
    }

    u32* __restrict__ o = support + (size_t)n * 50;
#pragma unroll
    for (int i = 0; i < 50; ++i) o[i] = packbf(acc[2*i], acc[2*i+1]);
}

// ---------------------------------------------------------------------------
// Kernel 2a: per-sample counting-sort into CSR order.
// ---------------------------------------------------------------------------
__global__ __launch_bounds__(256, 2)
void csr_build(const int* __restrict__ arow, const int* __restrict__ acol,
               const float* __restrict__ aval,
               int* __restrict__ offs, int2* __restrict__ csr)
{
    __shared__ int cnt[1024];
    __shared__ int part[256];
    __shared__ int offl[1024];

    const int b   = blockIdx.x;
    const int tid = threadIdx.x;
    const int*   rw = arow + b * 16384;
    const int*   cl = acol + b * 16384;
    const float* vl = aval + b * 16384;

    for (int i = tid; i < 1024; i += 256) cnt[i] = 0;
    __syncthreads();
    for (int e = tid; e < 16384; e += 256) atomicAdd(&cnt[rw[e]], 1);
    __syncthreads();

    int c[4]; int s = 0;
#pragma unroll
    for (int q = 0; q < 4; ++q) { c[q] = cnt[tid * 4 + q]; s += c[q]; }
    part[tid] = s;
    __syncthreads();
    for (int off = 1; off < 256; off <<= 1) {
        int v = (tid >= off) ? part[tid - off] : 0;
        __syncthreads();
        part[tid] += v;
        __syncthreads();
    }
    int run = part[tid] - s;
#pragma unroll
    for (int q = 0; q < 4; ++q) { offl[tid * 4 + q] = run; run += c[q]; }
    __syncthreads();

    for (int i = tid; i < 1024; i += 256) offs[b * 1025 + i] = offl[i];
    if (tid == 0) offs[b * 1025 + 1024] = 16384;

    int2* cs = csr + (size_t)b * 16384;
    for (int e = tid; e < 16384; e += 256) {
        const int r   = rw[e];
        const int pos = atomicAdd(&offl[r], 1);
        int2 cv; cv.x = cl[e]; cv.y = __float_as_int(vl[e]);
        cs[pos] = cv;
    }
}

// ---------------------------------------------------------------------------
// Kernel 2b: atomic-free CSR aggregate.  50 lanes/row.
// ---------------------------------------------------------------------------
__global__ __launch_bounds__(256, 4)
void spmm_agg(const int* __restrict__ offs, const int2* __restrict__ csr,
              const u32* __restrict__ support,
              const float* __restrict__ gcn_b, u32* __restrict__ seq)
{
    const int b    = blockIdx.y;
    const int lr   = threadIdx.x / 50;
    const int lane = threadIdx.x % 50;
    const int r    = blockIdx.x * 5 + lr;
    if (lr >= 5 || r >= 1024) return;

    const int e0 = offs[b * 1025 + r];
    const int e1 = offs[b * 1025 + r + 1];
    const int2* __restrict__ cs = csr + (size_t)b * 16384;
    const u32* __restrict__ supb = support + (size_t)b * 1024 * 50;

    float a0 = 0.f, a1 = 0.f;
    for (int e = e0; e < e1; ++e) {
        const int2 cv = cs[e];
        const float v = __int_as_float(cv.y);
        const u32 u = supb[(size_t)cv.x * 50 + lane];
        a0 = fmaf(v, bflo(u), a0);
        a1 = fmaf(v, bfhi(u), a1);
    }
    a0 += gcn_b[2 * lane];
    a1 += gcn_b[2 * lane + 1];
    seq[((size_t)b * 1024 + r) * 50 + lane] = packbf(a0, a1);
}

// ---------------------------------------------------------------------------
// gx GEMM body (shared by standalone chunk-0 kernel and fused kernel).
// gx output is bf16-packed: gx[m][g*50+jw] packs units (2jw, 2jw+1) of gate g.
// ---------------------------------------------------------------------------
__device__ __forceinline__
void gemm_body(int gi, int tid, const u32* __restrict__ seq,
               const float* __restrict__ w_ih, const float* __restrict__ b_ih,
               u32* __restrict__ gxW, int c0, int ctl, int CT, float* wl)
{
    const int g    = gi % 3;
    const int tile = gi / 3;

    for (int i = tid; i < 10000; i += 256)
        wl[(i % 100) * 100 + (i / 100)] = w_ih[g * 10000 + i];   // transpose
    __syncthreads();

    const int m = tile * 256 + tid;              // 0 .. 128*CT-1
    const int b = m >> ctl;
    const int t = m & (CT - 1);
    const uint2* sr2 = (const uint2*)(seq + ((size_t)b * 1024 + c0 + t) * 50);

    float acc[100];
    const float4* bi4 = (const float4*)(b_ih + g * 100);
#pragma unroll
    for (int j4 = 0; j4 < 25; ++j4) {
        const float4 bv = bi4[j4];
        acc[j4*4+0] = bv.x; acc[j4*4+1] = bv.y; acc[j4*4+2] = bv.z; acc[j4*4+3] = bv.w;
    }

    for (int kk = 0; kk < 25; ++kk) {
        const uint2 up = sr2[kk];
        const float xs[4] = { bflo(up.x), bfhi(up.x), bflo(up.y), bfhi(up.y) };
#pragma unroll
        for (int q = 0; q < 4; ++q) {
            const float* wrow = &wl[(kk * 4 + q) * 100];
            const float xq = xs[q];
#pragma unroll
            for (int j4 = 0; j4 < 25; ++j4) {
                const float4 w4 = *(const float4*)(wrow + j4 * 4);
                acc[j4*4+0] = fmaf(xq, w4.x, acc[j4*4+0]);
                acc[j4*4+1] = fmaf(xq, w4.y, acc[j4*4+1]);
                acc[j4*4+2] = fmaf(xq, w4.z, acc[j4*4+2]);
                acc[j4*4+3] = fmaf(xq, w4.w, acc[j4*4+3]);
            }
        }
    }

    u32* og = gxW + (size_t)m * 150 + g * 50;
#pragma unroll
    for (int i = 0; i < 50; ++i) og[i] = packbf(acc[2*i], acc[2*i+1]);
}

__global__ __launch_bounds__(256, 2)
void gx_gemm0(const u32* __restrict__ seq, const float* __restrict__ w_ih,
              const float* __restrict__ b_ih, u32* __restrict__ gxW,
              int c0, int ctl, int CT)
{
    __shared__ float wl[10000];
    gemm_body(blockIdx.x, threadIdx.x, seq, w_ih, b_ih, gxW, c0, ctl, CT, wl);
}

// ---------------------------------------------------------------------------
// Fused kernel: blocks [0,gruBlocks) run the GRU recurrence for chunk c
// (2 samples/block, 1 barrier/step, h ping-pong in LDS, gx prefetch dist 2);
// blocks [gruBlocks, ...) compute gx for chunk c+1 into the other buffer.
// ---------------------------------------------------------------------------
__global__ __launch_bounds__(256, 1)
void fused_kernel(const u32* __restrict__ seq, const float* __restrict__ w_ih,
                  const float* __restrict__ b_ih, u32* __restrict__ gxW, int c0g,
                  const u32* __restrict__ gxR, const float* __restrict__ w_hh,
                  const float* __restrict__ b_hh, float* __restrict__ hg,
                  const float* __restrict__ fc1_w, const float* __restrict__ fc1_b,
                  float* __restrict__ out, int first, int last,
                  int CT, int ctl, int gruBlocks)
{
    __shared__ float wl[10000];
    __shared__ float h_sh[2][2][100];            // [pingpong][half][unit]

    if ((int)blockIdx.x >= gruBlocks) {
        gemm_body(blockIdx.x - gruBlocks, threadIdx.x, seq, w_ih, b_ih, gxW,
                  c0g, ctl, CT, wl);
        return;
    }

    // ---------------- GRU part ----------------
    const int tid  = threadIdx.x;
    const int half = tid >> 7;                   // 2 samples per block
    const int j    = tid & 127;
    const int samp = blockIdx.x * 2 + half;
    const int odd  = j & 1;

    f2 wr[50], wz[50], wn[50];
    float bhr = 0.f, bhz = 0.f, bhn = 0.f;
    if (j < 100) {
        const float4* r4 = (const float4*)(w_hh + (size_t)j * 100);
        const float4* z4 = (const float4*)(w_hh + (size_t)(100 + j) * 100);
        const float4* n4 = (const float4*)(w_hh + (size_t)(200 + j) * 100);
#pragma unroll
        for (int kk = 0; kk < 25; ++kk) {
            const float4 a = r4[kk]; wr[2*kk] = (f2){a.x, a.y}; wr[2*kk+1] = (f2){a.z, a.w};
            const float4 b = z4[kk]; wz[2*kk] = (f2){b.x, b.y}; wz[2*kk+1] = (f2){b.z, b.w};
            const float4 c = n4[kk]; wn[2*kk] = (f2){c.x, c.y}; wn[2*kk+1] = (f2){c.z, c.w};
        }
        bhr = b_hh[j]; bhz = b_hh[100 + j]; bhn = b_hh[200 + j];
        h_sh[0][half][j] = first ? 0.f : hg[samp * 100 + j];
    }
    __syncthreads();

    const u32* gp = gxR + (size_t)samp * CT * 150 + (j >> 1);
    u32 a0 = 0, a1 = 0, a2 = 0, b0 = 0, b1 = 0, b2 = 0;
    if (j < 100) {
        a0 = gp[0];   a1 = gp[50];  a2 = gp[100];          // t = 0
        b0 = gp[150]; b1 = gp[200]; b2 = gp[250];          // t = 1
    }
    int par = 0;

    auto step = [&](u32 c0, u32 c1, u32 c2) {
        if (j < 100) {
            const float* hc = &h_sh[par][half][0];
            f2 sr0 = {0.f,0.f}, sr1 = {0.f,0.f};
            f2 sz0 = {0.f,0.f}, sz1 = {0.f,0.f};
            f2 sn0 = {0.f,0.f}, sn1 = {0.f,0.f};
#pragma unroll
            for (int kk = 0; kk < 25; ++kk) {
                const float4 h4 = *(const float4*)(hc + kk * 4);
                const f2 hA = (f2){h4.x, h4.y};
                const f2 hB = (f2){h4.z, h4.w};
                sr0 += wr[2*kk] * hA; sr1 += wr[2*kk+1] * hB;
                sz0 += wz[2*kk] * hA; sz1 += wz[2*kk+1] * hB;
                sn0 += wn[2*kk] * hA; sn1 += wn[2*kk+1] * hB;
            }
            const float ghr = (sr0.x + sr0.y) + (sr1.x + sr1.y) + bhr;
            const float ghz = (sz0.x + sz0.y) + (sz1.x + sz1.y) + bhz;
            const float ghn = (sn0.x + sn0.y) + (sn1.x + sn1.y) + bhn;
            const float gxr = odd ? bfhi(c0) : bflo(c0);
            const float gxz = odd ? bfhi(c1) : bflo(c1);
            const float gxn = odd ? bfhi(c2) : bflo(c2);
            const float r = sigm(gxr + ghr);
            const float z = sigm(gxz + ghz);
            const float n = tanh_fast(gxn + r * ghn);
            h_sh[par ^ 1][half][j] = (1.f - z) * n + z * hc[j];
        }
        __syncthreads();
        par ^= 1;
    };

    for (int t = 0; t < CT; t += 2) {
        {   // step t (regs a), prefetch t+2
            const u32 c0 = a0, c1 = a1, c2 = a2;
            if (j < 100 && t + 2 < CT) {
                const u32* q = gp + (size_t)(t + 2) * 150;
                a0 = q[0]; a1 = q[50]; a2 = q[100];
            }
            step(c0, c1, c2);
        }
        {   // step t+1 (regs b), prefetch t+3
            const u32 c0 = b0, c1 = b1, c2 = b2;
            if (j < 100 && t + 3 < CT) {
                const u32* q = gp + (size_t)(t + 3) * 150;
                b0 = q[0]; b1 = q[50]; b2 = q[100];
            }
            step(c0, c1, c2);
        }
    }

    if (j < 100) {
        const float* hc = &h_sh[par][half][0];
        hg[samp * 100 + j] = hc[j];
        if (last) {
            const float4* fw = (const float4*)(fc1_w + (size_t)j * 100);
            float s0 = 0.f, s1 = 0.f, s2 = 0.f, s3 = 0.f;
#pragma unroll
            for (int kk = 0; kk < 25; ++kk) {
                const float4 wv = fw[kk];
                const float4 hv = *(const float4*)(hc + kk * 4);
                s0 = fmaf(wv.x, hv.x, s0);
                s1 = fmaf(wv.y, hv.y, s1);
                s2 = fmaf(wv.z, hv.z, s2);
                s3 = fmaf(wv.w, hv.w, s3);
            }
            const float s = (s0 + s1) + (s2 + s3) + fc1_b[j];
            out[samp * 100 + j] = fmaxf(s, 0.f);
        }
    }
}

// ---------------------------------------------------------------------------
extern "C" void kernel_launch(void* const* d_in, const int* in_sizes, int n_in,
                              void* d_out, int out_size, void* d_ws, size_t ws_size,
                              hipStream_t stream)
{
    const int*   neighbors = (const int*)  d_in[0];
    const int*   adj_row   = (const int*)  d_in[1];
    const int*   adj_col   = (const int*)  d_in[2];
    const float* adj_val   = (const float*)d_in[3];
    const float* emb       = (const float*)d_in[4];
    const float* gcn_w     = (const float*)d_in[5];
    const float* gcn_b     = (const float*)d_in[6];
    const float* w_ih      = (const float*)d_in[7];
    const float* w_hh      = (const float*)d_in[8];
    const float* b_ih      = (const float*)d_in[9];
    const float* b_hh      = (const float*)d_in[10];
    const float* fc1_w     = (const float*)d_in[11];
    const float* fc1_b     = (const float*)d_in[12];
    float* out = (float*)d_out;

    char* ws = (char*)d_ws;
    const size_t support_bytes = (size_t)128 * 1024 * 100 * 2;   // 26,214,400
    const size_t seq_bytes     = support_bytes;                  // 26,214,400
    const size_t hg_bytes      = 128 * 100 * 4;                  // 51,200
    const size_t offs_bytes    = (size_t)128 * 1025 * 4;         // 524,800

    u32*   support = (u32*)ws;
    u32*   seq     = (u32*)(ws + support_bytes);
    float* hg      = (float*)(ws + support_bytes + seq_bytes);
    char*  scratch = ws + support_bytes + seq_bytes + hg_bytes;
    const size_t scratch_avail = ws_size - (support_bytes + seq_bytes + hg_bytes);

    // CSR arrays (phase 1) and the gx double buffer (phase 2) share scratch.
    int*  offs = (int*)scratch;
    int2* csr  = (int2*)(scratch + offs_bytes);

    // largest CT whose two bf16 gx buffers fit scratch
    int CT = 256, ctl = 8;
    while (CT > 8 && 2 * (size_t)128 * CT * 300 * 2 > scratch_avail) { CT >>= 1; --ctl; }
    const size_t gx_bytes = (size_t)128 * CT * 300 * 2;
    u32* gxA = (u32*)scratch;
    u32* gxB = (u32*)(scratch + gx_bytes);

    gcn_kernel<<<512, 256, 0, stream>>>(neighbors, emb, gcn_w, support);
    csr_build<<<128, 256, 0, stream>>>(adj_row, adj_col, adj_val, offs, csr);
    spmm_agg<<<dim3(205, 128), 256, 0, stream>>>(offs, csr, support, gcn_b, seq);

    const int nch = 1024 / CT;
    const int gemmBlocks = 3 * (CT / 2);        // (128*CT/256) tiles * 3 gates
    const int gruBlocks  = 64;                  // 2 samples per block

    gx_gemm0<<<gemmBlocks, 256, 0, stream>>>(seq, w_ih, b_ih, gxA, 0, ctl, CT);

    for (int c = 0; c < nch; ++c) {
        u32* gxRc = (c & 1) ? gxB : gxA;
        u32* gxWc = (c & 1) ? gxA : gxB;
        const int haveGemm = (c + 1 < nch);
        const int grid = gruBlocks + (haveGemm ? gemmBlocks : 0);
        fused_kernel<<<grid, 256, 0, stream>>>(seq, w_ih, b_ih, gxWc, (c + 1) * CT,
                                               gxRc, w_hh, b_hh, hg, fc1_w, fc1_b, out,
                                               (c == 0) ? 1 : 0, (c == nch - 1) ? 1 : 0,
                                               CT, ctl, gruBlocks);
    }
}

// Round 4
// 1322.751 us; speedup vs baseline: 1.4154x; 1.4154x over previous
//
#include <hip/hip_runtime.h>
#include <hip/hip_bf16.h>

// Problem constants: B=128, N=1024, E=16384, ENTITY=100000, EMB=100, HID=100

typedef unsigned int u32;
typedef float f2 __attribute__((ext_vector_type(2)));

__device__ __forceinline__ float bflo(u32 u) {
    union { u32 i; float f; } v; v.i = u << 16; return v.f;
}
__device__ __forceinline__ float bfhi(u32 u) {
    union { u32 i; float f; } v; v.i = u & 0xffff0000u; return v.f;
}
__device__ __forceinline__ u32 f2bf1(float f) {
    union { float f; u32 u; } v; v.f = f;
    return (v.u + 0x7fffu + ((v.u >> 16) & 1u)) >> 16;   // RNE
}
__device__ __forceinline__ u32 packbf(float a, float b) {
    return f2bf1(a) | (f2bf1(b) << 16);
}
__device__ __forceinline__ float sigm(float x) { return 1.f / (1.f + __expf(-x)); }
__device__ __forceinline__ float tanh_fast(float x) {
    float e = __expf(2.f * x);
    return 1.f - 2.f / (e + 1.f);
}

// ---------------------------------------------------------------------------
// Kernel 1: embedding gather + GCN matmul.  support[n][h] (bf16 packed u32)
// ---------------------------------------------------------------------------
__global__ __launch_bounds__(256, 2)
void gcn_kernel(const int* __restrict__ nb, const float* __restrict__ emb,
                const float* __restrict__ w, u32* __restrict__ support)
{
    __shared__ float wl[10000];
    for (int i = threadIdx.x; i < 10000; i += 256) wl[i] = w[i];
    __syncthreads();

    const int n = blockIdx.x * 256 + threadIdx.x;
    const long long row = nb[n];
    const float4* __restrict__ xr = (const float4*)(emb + row * 100);

    float acc[100];
#pragma unroll
    for (int h = 0; h < 100; ++h) acc[h] = 0.f;

    for (int kk = 0; kk < 25; ++kk) {
        const float4 xv = xr[kk];
        const float xs[4] = { xv.x, xv.y, xv.z, xv.w };
#pragma unroll
        for (int q = 0; q < 4; ++q) {
            const float* wrow = &wl[(kk * 4 + q) * 100];
            const float xq = xs[q];
#pragma unroll
            for (int h4 = 0; h4 < 25; ++h4) {
                const float4 w4 = *(const float4*)(wrow + h4 * 4);
                acc[h4*4+0] = fmaf(xq, w4.x, acc[h4*4+0]);
                acc[h4*4+1] = fmaf(xq, w4.y, acc[h4*4+1]);
                acc[h4*4+2] = fmaf(xq, w4.z, acc[h4*4+2]);
                acc[h4*4+3] = fmaf(xq, w4.w, acc[h4*4+3]);
            }
        }
    }

    u32* __restrict__ o = support + (size_t)n * 50;
#pragma unroll
    for (int i = 0; i < 50; ++i) o[i] = packbf(acc[2*i], acc[2*i+1]);
}

// ---------------------------------------------------------------------------
// Kernel 2a: per-sample counting-sort into CSR order.
// ---------------------------------------------------------------------------
__global__ __launch_bounds__(256, 2)
void csr_build(const int* __restrict__ arow, const int* __restrict__ acol,
               const float* __restrict__ aval,
               int* __restrict__ offs, int2* __restrict__ csr)
{
    __shared__ int cnt[1024];
    __shared__ int part[256];
    __shared__ int offl[1024];

    const int b   = blockIdx.x;
    const int tid = threadIdx.x;
    const int*   rw = arow + b * 16384;
    const int*   cl = acol + b * 16384;
    const float* vl = aval + b * 16384;

    for (int i = tid; i < 1024; i += 256) cnt[i] = 0;
    __syncthreads();
    for (int e = tid; e < 16384; e += 256) atomicAdd(&cnt[rw[e]], 1);
    __syncthreads();

    int c[4]; int s = 0;
#pragma unroll
    for (int q = 0; q < 4; ++q) { c[q] = cnt[tid * 4 + q]; s += c[q]; }
    part[tid] = s;
    __syncthreads();
    for (int off = 1; off < 256; off <<= 1) {
        int v = (tid >= off) ? part[tid - off] : 0;
        __syncthreads();
        part[tid] += v;
        __syncthreads();
    }
    int run = part[tid] - s;
#pragma unroll
    for (int q = 0; q < 4; ++q) { offl[tid * 4 + q] = run; run += c[q]; }
    __syncthreads();

    for (int i = tid; i < 1024; i += 256) offs[b * 1025 + i] = offl[i];
    if (tid == 0) offs[b * 1025 + 1024] = 16384;

    int2* cs = csr + (size_t)b * 16384;
    for (int e = tid; e < 16384; e += 256) {
        const int r   = rw[e];
        const int pos = atomicAdd(&offl[r], 1);
        int2 cv; cv.x = cl[e]; cv.y = __float_as_int(vl[e]);
        cs[pos] = cv;
    }
}

// ---------------------------------------------------------------------------
// Kernel 2b: atomic-free CSR aggregate.  50 lanes/row.
// ---------------------------------------------------------------------------
__global__ __launch_bounds__(256, 4)
void spmm_agg(const int* __restrict__ offs, const int2* __restrict__ csr,
              const u32* __restrict__ support,
              const float* __restrict__ gcn_b, u32* __restrict__ seq)
{
    const int b    = blockIdx.y;
    const int lr   = threadIdx.x / 50;
    const int lane = threadIdx.x % 50;
    const int r    = blockIdx.x * 5 + lr;
    if (lr >= 5 || r >= 1024) return;

    const int e0 = offs[b * 1025 + r];
    const int e1 = offs[b * 1025 + r + 1];
    const int2* __restrict__ cs = csr + (size_t)b * 16384;
    const u32* __restrict__ supb = support + (size_t)b * 1024 * 50;

    float a0 = 0.f, a1 = 0.f;
    for (int e = e0; e < e1; ++e) {
        const int2 cv = cs[e];
        const float v = __int_as_float(cv.y);
        const u32 u = supb[(size_t)cv.x * 50 + lane];
        a0 = fmaf(v, bflo(u), a0);
        a1 = fmaf(v, bfhi(u), a1);
    }
    a0 += gcn_b[2 * lane];
    a1 += gcn_b[2 * lane + 1];
    seq[((size_t)b * 1024 + r) * 50 + lane] = packbf(a0, a1);
}

// ---------------------------------------------------------------------------
// Kernel 3: gx GEMM.  gx[m][g*50+jw] packs units (2jw,2jw+1) of gate g, bf16.
// m = b*CT + t (local to the window being computed).
// ---------------------------------------------------------------------------
__global__ __launch_bounds__(256, 2)
void gx_gemm0(const u32* __restrict__ seq, const float* __restrict__ w_ih,
              const float* __restrict__ b_ih, u32* __restrict__ gxW,
              int c0, int ctl, int CT)
{
    __shared__ float wl[10000];
    const int g    = blockIdx.x % 3;
    const int tile = blockIdx.x / 3;
    const int tid  = threadIdx.x;

    for (int i = tid; i < 10000; i += 256)
        wl[(i % 100) * 100 + (i / 100)] = w_ih[g * 10000 + i];   // transpose
    __syncthreads();

    const int m = tile * 256 + tid;              // 0 .. 128*CT-1
    const int b = m >> ctl;
    const int t = m & (CT - 1);
    const uint2* sr2 = (const uint2*)(seq + ((size_t)b * 1024 + c0 + t) * 50);

    float acc[100];
    const float4* bi4 = (const float4*)(b_ih + g * 100);
#pragma unroll
    for (int j4 = 0; j4 < 25; ++j4) {
        const float4 bv = bi4[j4];
        acc[j4*4+0] = bv.x; acc[j4*4+1] = bv.y; acc[j4*4+2] = bv.z; acc[j4*4+3] = bv.w;
    }

    for (int kk = 0; kk < 25; ++kk) {
        const uint2 up = sr2[kk];
        const float xs[4] = { bflo(up.x), bfhi(up.x), bflo(up.y), bfhi(up.y) };
#pragma unroll
        for (int q = 0; q < 4; ++q) {
            const float* wrow = &wl[(kk * 4 + q) * 100];
            const float xq = xs[q];
#pragma unroll
            for (int j4 = 0; j4 < 25; ++j4) {
                const float4 w4 = *(const float4*)(wrow + j4 * 4);
                acc[j4*4+0] = fmaf(xq, w4.x, acc[j4*4+0]);
                acc[j4*4+1] = fmaf(xq, w4.y, acc[j4*4+1]);
                acc[j4*4+2] = fmaf(xq, w4.z, acc[j4*4+2]);
                acc[j4*4+3] = fmaf(xq, w4.w, acc[j4*4+3]);
            }
        }
    }

    u32* og = gxW + (size_t)m * 150 + g * 50;
#pragma unroll
    for (int i = 0; i < 50; ++i) og[i] = packbf(acc[2*i], acc[2*i+1]);
}

// ---------------------------------------------------------------------------
// Kernel 4 (v3): GRU recurrence, 1 sample per block, 640 threads (10 waves).
// thread (p = tid/320, r = tid%320): holds 50 fp32 weights of W_hh row r
// (float4-groups q with q%2==p  ->  all LDS reads 16B-aligned), computes a
// k-half partial into ps[]; threads j<100 combine partials + gates.
// ONE h buffer (only thread j touches h[j] between the two barriers).
// gx (bf16-packed) prefetched in registers, distance 2.
// ---------------------------------------------------------------------------
__global__ __launch_bounds__(640, 1)
void gru_v3(const u32* __restrict__ gxR, size_t sampStride,
            const float* __restrict__ w_hh, const float* __restrict__ b_hh,
            float* __restrict__ hg, const float* __restrict__ fc1_w,
            const float* __restrict__ fc1_b, float* __restrict__ out,
            int first, int last, int CT)
{
    __shared__ float h[100];
    __shared__ float ps[600];

    const int tid  = threadIdx.x;
    const int samp = blockIdx.x;
    const int p    = tid / 320;            // wave-uniform (waves 0-4: p0, 5-9: p1)
    const int r    = tid - p * 320;        // row 0..319, active if <300
    const bool rowAct = (r < 300);
    const int NG   = 13 - p;               // p0: 13 float4-groups, p1: 12

    // ---- one-time: weights into registers (52 VGPRs max) ----
    f2 wk[26];
    if (rowAct) {
        const float* wrow = w_hh + (size_t)r * 100;
#pragma unroll
        for (int i = 0; i < 13; ++i) {
            if (i < NG) {
                const int q = 2 * i + p;
                const float4 wv = *(const float4*)(wrow + 4 * q);
                wk[2*i]   = (f2){wv.x, wv.y};
                wk[2*i+1] = (f2){wv.z, wv.w};
            }
        }
    }

    float bhr = 0.f, bhz = 0.f, bhn = 0.f;
    if (tid < 100) {
        bhr = b_hh[tid]; bhz = b_hh[100 + tid]; bhn = b_hh[200 + tid];
        h[tid] = first ? 0.f : hg[samp * 100 + tid];
    }
    __syncthreads();

    const int odd = tid & 1;
    const u32* gp = gxR + (size_t)samp * sampStride + (tid >> 1);
    u32 a0 = 0, a1 = 0, a2 = 0, b0 = 0, b1 = 0, b2 = 0;
    if (tid < 100) {
        a0 = gp[0];   a1 = gp[50];  a2 = gp[100];        // t = 0
        b0 = gp[150]; b1 = gp[200]; b2 = gp[250];        // t = 1
    }

    auto stepf = [&](int t, u32& x0, u32& x1, u32& x2) {
        // phase A: k-half dot against h (same-address b128 broadcasts)
        float sum = 0.f;
        if (rowAct) {
            f2 acc0 = {0.f, 0.f}, acc1 = {0.f, 0.f};
#pragma unroll
            for (int i = 0; i < 13; ++i) {
                if (i < NG) {
                    const int q = 2 * i + p;
                    const float4 hv = *(const float4*)(&h[4 * q]);
                    acc0 += wk[2*i]   * (f2){hv.x, hv.y};
                    acc1 += wk[2*i+1] * (f2){hv.z, hv.w};
                }
            }
            sum = (acc0.x + acc0.y) + (acc1.x + acc1.y);
        }
        // capture this step's gx, then prefetch t+2 into the same regs
        const u32 c0 = x0, c1 = x1, c2 = x2;
        if (tid < 100 && t + 2 < CT) {
            const u32* q2 = gp + (size_t)(t + 2) * 150;
            x0 = q2[0]; x1 = q2[50]; x2 = q2[100];
        }
        if (rowAct) ps[p * 300 + r] = sum;
        __syncthreads();
        // phase B: gates (threads 0..99)
        if (tid < 100) {
            const float ghr = ps[tid]       + ps[300 + tid] + bhr;
            const float ghz = ps[100 + tid] + ps[400 + tid] + bhz;
            const float ghn = ps[200 + tid] + ps[500 + tid] + bhn;
            const float gxr = odd ? bfhi(c0) : bflo(c0);
            const float gxz = odd ? bfhi(c1) : bflo(c1);
            const float gxn = odd ? bfhi(c2) : bflo(c2);
            const float rg = sigm(gxr + ghr);
            const float zg = sigm(gxz + ghz);
            const float ng = tanh_fast(gxn + rg * ghn);
            h[tid] = (1.f - zg) * ng + zg * h[tid];
        }
        __syncthreads();
    };

    for (int t = 0; t < CT; t += 2) {
        stepf(t,     a0, a1, a2);
        stepf(t + 1, b0, b1, b2);
    }

    if (tid < 100) {
        hg[samp * 100 + tid] = h[tid];
        if (last) {
            const float4* fw = (const float4*)(fc1_w + (size_t)tid * 100);
            float s0 = 0.f, s1 = 0.f, s2 = 0.f, s3 = 0.f;
#pragma unroll
            for (int kk = 0; kk < 25; ++kk) {
                const float4 wv = fw[kk];
                const float4 hv = *(const float4*)(&h[kk * 4]);
                s0 = fmaf(wv.x, hv.x, s0);
                s1 = fmaf(wv.y, hv.y, s1);
                s2 = fmaf(wv.z, hv.z, s2);
                s3 = fmaf(wv.w, hv.w, s3);
            }
            const float s = (s0 + s1) + (s2 + s3) + fc1_b[tid];
            out[samp * 100 + tid] = fmaxf(s, 0.f);
        }
    }
}

// ---------------------------------------------------------------------------
extern "C" void kernel_launch(void* const* d_in, const int* in_sizes, int n_in,
                              void* d_out, int out_size, void* d_ws, size_t ws_size,
                              hipStream_t stream)
{
    const int*   neighbors = (const int*)  d_in[0];
    const int*   adj_row   = (const int*)  d_in[1];
    const int*   adj_col   = (const int*)  d_in[2];
    const float* adj_val   = (const float*)d_in[3];
    const float* emb       = (const float*)d_in[4];
    const float* gcn_w     = (const float*)d_in[5];
    const float* gcn_b     = (const float*)d_in[6];
    const float* w_ih      = (const float*)d_in[7];
    const float* w_hh      = (const float*)d_in[8];
    const float* b_ih      = (const float*)d_in[9];
    const float* b_hh      = (const float*)d_in[10];
    const float* fc1_w     = (const float*)d_in[11];
    const float* fc1_b     = (const float*)d_in[12];
    float* out = (float*)d_out;

    char* ws = (char*)d_ws;
    const size_t seq_bytes     = (size_t)128 * 1024 * 50 * 4;    // 26,214,400
    const size_t hg_bytes      = 128 * 100 * 4;                  // 51,200
    const size_t support_bytes = (size_t)128 * 1024 * 50 * 4;    // 26,214,400
    const size_t offs_bytes    = (size_t)128 * 1025 * 4;         // 524,800

    u32*   seq = (u32*)ws;
    float* hg  = (float*)(ws + seq_bytes);
    char*  rest = ws + seq_bytes + hg_bytes;
    const size_t rest_avail = ws_size - seq_bytes - hg_bytes;

    // Phase 1 (both modes): support + CSR live in `rest` (43.5 MB), all dead
    // before any gx is written over the same region.
    u32*  support = (u32*)rest;
    int*  offs    = (int*)(rest + support_bytes);
    int2* csr     = (int2*)(rest + support_bytes + offs_bytes);

    gcn_kernel<<<512, 256, 0, stream>>>(neighbors, emb, gcn_w, support);
    csr_build<<<128, 256, 0, stream>>>(adj_row, adj_col, adj_val, offs, csr);
    spmm_agg<<<dim3(205, 128), 256, 0, stream>>>(offs, csr, support, gcn_b, seq);

    const size_t gx_full = (size_t)128 * 1024 * 150 * 4;         // 78,643,200
    u32* gx = (u32*)rest;

    if (rest_avail >= gx_full) {
        // full-window: one GEMM dispatch, one 1024-step GRU dispatch
        gx_gemm0<<<1536, 256, 0, stream>>>(seq, w_ih, b_ih, gx, 0, 10, 1024);
        gru_v3<<<128, 640, 0, stream>>>(gx, (size_t)1024 * 150, w_hh, b_hh, hg,
                                        fc1_w, fc1_b, out, 1, 1, 1024);
    } else {
        // chunked fallback
        int CT = 512, ctl = 9;
        while (CT > 8 && (size_t)128 * CT * 150 * 4 > rest_avail) { CT >>= 1; --ctl; }
        const int nch = 1024 / CT;
        for (int c = 0; c < nch; ++c) {
            gx_gemm0<<<3 * (128 * CT / 256), 256, 0, stream>>>(seq, w_ih, b_ih, gx,
                                                               c * CT, ctl, CT);
            gru_v3<<<128, 640, 0, stream>>>(gx, (size_t)CT * 150, w_hh, b_hh, hg,
                                            fc1_w, fc1_b, out,
                                            (c == 0) ? 1 : 0, (c == nch - 1) ? 1 : 0, CT);
        }
    }
}